// Round 20
// baseline (334.392 us; speedup 1.0000x reference)
//
#include <hip/hip_runtime.h>
#include <math.h>

#define BB 8
#define SS 512
#define FF 64
#define DD 512
#define II 1024
#define NHH 8
#define KK 4
#define DHH 128
#define H1H 32
#define OUTO 24
#define BS (BB*SS)   // 4096

typedef unsigned short ushort;
typedef __attribute__((ext_vector_type(8))) short short8;
typedef __attribute__((ext_vector_type(8))) unsigned short ushort8;
typedef __attribute__((ext_vector_type(4))) unsigned short ushort4v;
typedef __attribute__((ext_vector_type(4))) float f32x4;

__device__ __forceinline__ float bf2f(ushort u) {
  return __uint_as_float(((unsigned int)u) << 16);
}
__device__ __forceinline__ ushort f2bf(float f) {
  unsigned int u = __float_as_uint(f);
  unsigned int r = u + 0x7fffu + ((u >> 16) & 1u);
  return (ushort)(r >> 16);
}

typedef __attribute__((address_space(1))) const void gvoid;
typedef __attribute__((address_space(3))) void lvoid;
__device__ __forceinline__ void async16(const void* g, void* l) {
  __builtin_amdgcn_global_load_lds((gvoid*)g, (lvoid*)l, 16, 0, 0);
}

// ---------------- fused prologue ----------------
// blocks 0..255: input proj + layer-0 LN (16 rows each)
// blocks 256..2583: weight transpose 64x64 tiles + gate pack, both layers
__global__ __launch_bounds__(256) void k_pre(const float* __restrict__ x,
                                             const float* __restrict__ w,
                                             const float* __restrict__ b,
                                             const float* __restrict__ lnw,
                                             const float* __restrict__ lnb,
                                             float* __restrict__ h,
                                             ushort* __restrict__ xn,
                                             const float* __restrict__ up_w,
                                             const float* __restrict__ q_w,
                                             const float* __restrict__ k_w,
                                             const float* __restrict__ v_w,
                                             const float* __restrict__ dn_w,
                                             const float* __restrict__ igw,
                                             const float* __restrict__ fgw,
                                             ushort* __restrict__ wt_up,
                                             ushort* __restrict__ wt_qk,
                                             ushort* __restrict__ wt_v,
                                             ushort* __restrict__ wt_dn,
                                             ushort* __restrict__ Wg) {
  int blk0 = blockIdx.x;
  int tid = threadIdx.x;
  if (blk0 < 256) {
    int r0 = blk0 * 16;
    __shared__ float xs[16][FF];
    for (int i = tid; i < 16 * FF; i += 256)
      xs[i >> 6][i & 63] = x[(size_t)(r0 + (i >> 6)) * FF + (i & 63)];
    __syncthreads();
    float acc0[16], acc1[16];
    float b0 = b[tid], b1 = b[tid + 256];
#pragma unroll
    for (int r = 0; r < 16; ++r) { acc0[r] = b0; acc1[r] = b1; }
    for (int f = 0; f < FF; ++f) {
      float w0 = w[(size_t)f * DD + tid];
      float w1 = w[(size_t)f * DD + tid + 256];
#pragma unroll
      for (int r = 0; r < 16; ++r) {
        float xv = xs[r][f];
        acc0[r] += xv * w0;
        acc1[r] += xv * w1;
      }
    }
#pragma unroll
    for (int r = 0; r < 16; ++r) {
      h[(size_t)(r0 + r) * DD + tid] = acc0[r];
      h[(size_t)(r0 + r) * DD + tid + 256] = acc1[r];
    }
    float s[16], q[16];
#pragma unroll
    for (int r = 0; r < 16; ++r) {
      s[r] = acc0[r] + acc1[r];
      q[r] = acc0[r] * acc0[r] + acc1[r] * acc1[r];
    }
#pragma unroll
    for (int off = 32; off; off >>= 1) {
#pragma unroll
      for (int r = 0; r < 16; ++r) {
        s[r] += __shfl_down(s[r], off);
        q[r] += __shfl_down(q[r], off);
      }
    }
    __shared__ float ssum[4][16], ssq[4][16];
    int wid = tid >> 6, lane = tid & 63;
    if (lane == 0) {
#pragma unroll
      for (int r = 0; r < 16; ++r) { ssum[wid][r] = s[r]; ssq[wid][r] = q[r]; }
    }
    __syncthreads();
    __shared__ float smean[16], srstd[16];
    if (tid < 16) {
      float ts = ssum[0][tid] + ssum[1][tid] + ssum[2][tid] + ssum[3][tid];
      float tq = ssq[0][tid] + ssq[1][tid] + ssq[2][tid] + ssq[3][tid];
      float mean = ts * (1.0f / DD);
      float var = tq * (1.0f / DD) - mean * mean;
      smean[tid] = mean;
      srstd[tid] = rsqrtf(var + 1e-5f);
    }
    __syncthreads();
    float w0 = lnw[tid], w1 = lnw[tid + 256];
    float bb0 = lnb[tid], bb1 = lnb[tid + 256];
#pragma unroll
    for (int r = 0; r < 16; ++r) {
      float mean = smean[r], rstd = srstd[r];
      xn[(size_t)(r0 + r) * DD + tid] = f2bf((acc0[r] - mean) * rstd * w0 + bb0);
      xn[(size_t)(r0 + r) * DD + tid + 256] = f2bf((acc1[r] - mean) * rstd * w1 + bb1);
    }
    return;
  }
  int blk = blk0 - 256;
  int l = blk / 1164;
  blk -= l * 1164;
  if (blk >= 1152) {
    const float* igwl = igw + (size_t)l * 3 * II * NHH;
    const float* fgwl = fgw + (size_t)l * 3 * II * NHH;
    ushort* Wgl = Wg + (size_t)l * 16 * 3 * II;
    int k = (blk - 1152) * 256 + tid;
    if (k < 3 * II) {
#pragma unroll
      for (int o = 0; o < NHH; ++o) {
        Wgl[(size_t)o * (3 * II) + k] = f2bf(igwl[(size_t)k * NHH + o]);
        Wgl[(size_t)(NHH + o) * (3 * II) + k] = f2bf(fgwl[(size_t)k * NHH + o]);
      }
    }
    return;
  }
  const float* src; ushort* dst; int N, Kd, t;
  if (blk < 256)       { src = up_w + (size_t)l * DD * 2 * II; dst = wt_up + (size_t)l * 1048576; N = 2048; Kd = 512;  t = blk; }
  else if (blk < 512)  { src = q_w + (size_t)l * II * II;  dst = wt_qk + (size_t)l * 2097152; N = 1024; Kd = 1024; t = blk - 256; }
  else if (blk < 768)  { src = k_w + (size_t)l * II * II;  dst = wt_qk + (size_t)l * 2097152 + 1024 * 1024; N = 1024; Kd = 1024; t = blk - 512; }
  else if (blk < 1024) { src = v_w + (size_t)l * II * II;  dst = wt_v + (size_t)l * 1048576;  N = 1024; Kd = 1024; t = blk - 768; }
  else                 { src = dn_w + (size_t)l * II * DD; dst = wt_dn + (size_t)l * 524288;  N = 512;  Kd = 1024; t = blk - 1024; }
  int ntn = N >> 6;
  int n0 = (t % ntn) * 64, k0 = (t / ntn) * 64;
  __shared__ float tb[64][65];
  int c4 = (tid & 15) * 4, r16 = tid >> 4;
#pragma unroll
  for (int p = 0; p < 4; ++p) {
    int row = r16 + p * 16;
    float4 v = *(const float4*)&src[(size_t)(k0 + row) * N + n0 + c4];
    tb[row][c4 + 0] = v.x;
    tb[row][c4 + 1] = v.y;
    tb[row][c4 + 2] = v.z;
    tb[row][c4 + 3] = v.w;
  }
  __syncthreads();
#pragma unroll
  for (int p = 0; p < 4; ++p) {
    int nrow = r16 + p * 16;
    ushort4v o;
#pragma unroll
    for (int j = 0; j < 4; ++j) o[j] = f2bf(tb[c4 + j][nrow]);
    *(ushort4v*)&dst[(size_t)(n0 + nrow) * Kd + k0 + c4] = o;
  }
}

// ---------------- row layernorm over D=512 -> bf16 out ----------------
__global__ __launch_bounds__(256) void k_layernorm(const float* __restrict__ in,
                                                   const float* __restrict__ w,
                                                   const float* __restrict__ b,
                                                   ushort* __restrict__ out) {
  int row = blockIdx.x;
  int tid = threadIdx.x;
  float v0 = in[(size_t)row * DD + tid];
  float v1 = in[(size_t)row * DD + tid + 256];
  float s = v0 + v1, sq = v0 * v0 + v1 * v1;
  for (int off = 32; off; off >>= 1) {
    s += __shfl_down(s, off);
    sq += __shfl_down(sq, off);
  }
  __shared__ float ss[4], sqs[4];
  int wid = tid >> 6, lane = tid & 63;
  if (lane == 0) { ss[wid] = s; sqs[wid] = sq; }
  __syncthreads();
  if (tid == 0) {
    ss[0] = ss[0] + ss[1] + ss[2] + ss[3];
    sqs[0] = sqs[0] + sqs[1] + sqs[2] + sqs[3];
  }
  __syncthreads();
  float mean = ss[0] * (1.0f / DD);
  float var = sqs[0] * (1.0f / DD) - mean * mean;
  float r = rsqrtf(var + 1e-5f);
  out[(size_t)row * DD + tid] = f2bf((v0 - mean) * r * w[tid] + b[tid]);
  out[(size_t)row * DD + tid + 256] = f2bf((v1 - mean) * r * w[tid + 256] + b[tid + 256]);
}

// swizzle helpers (per-thread constants)
__device__ __forceinline__ int swz_scol(int lane) {
  return (((lane & 3) ^ ((lane >> 3) & 3)) * 8);
}
__device__ __forceinline__ int swz_fk(int lane) {
  return ((((lane >> 4) ^ (lane >> 1)) & 3) * 8);
}
__device__ __forceinline__ void xcd_swz(int* bx, int* by) {
  int gx = gridDim.x;
  int nwg = gx * gridDim.y;
  int orig = blockIdx.y * gx + blockIdx.x;
  int q = nwg >> 3;
  int wgid = (orig & 7) * q + (orig >> 3);
  *bx = wgid % gx;
  *by = wgid / gx;
}

// ---------------- up GEMM: 4 waves x (64x64), 128x128 tile, ring-3, unrolled (nkt=16) -----
__global__ __launch_bounds__(256) void k_gemm_up(const ushort* __restrict__ A,
                                                 const ushort* __restrict__ Bt,
                                                 ushort* __restrict__ Cb) {
  __shared__ ushort As[3][4096];
  __shared__ ushort Bs[3][4096];
  int tid = threadIdx.x;
  int wave = tid >> 6, lane = tid & 63;
  int wm = wave >> 1, wn = wave & 1;
  int bx, by; xcd_swz(&bx, &by);
  int m0 = by * 128, n0 = bx * 128;
  int scol = swz_scol(lane);
  const ushort* Ag1 = A + (size_t)(m0 + wave * 32 + (lane >> 2)) * DD + scol;
  const ushort* Ag2 = Ag1 + (size_t)16 * DD;
  const ushort* Bg1 = Bt + (size_t)(n0 + wave * 32 + (lane >> 2)) * DD + scol;
  const ushort* Bg2 = Bg1 + (size_t)16 * DD;
  int woff = wave * 1024;
  int l15 = lane & 15, fk = swz_fk(lane);
  int apo = (wm * 64 + l15) * 32 + fk;
  int bpo = (wn * 64 + l15) * 32 + fk;
  f32x4 acc[4][4] = {};
  const int nkt = DD / 32;   // 16
#define STAGEU(p) { int kt_ = (p) * 32; int bi_ = (p) % 3; \
    async16(Ag1 + kt_, &As[0][0] + bi_ * 4096 + woff); \
    async16(Ag2 + kt_, &As[0][0] + bi_ * 4096 + woff + 512); \
    async16(Bg1 + kt_, &Bs[0][0] + bi_ * 4096 + woff); \
    async16(Bg2 + kt_, &Bs[0][0] + bi_ * 4096 + woff + 512); }
  STAGEU(0);
  STAGEU(1);
#pragma unroll
  for (int it = 0; it < nkt; ++it) {
    if (it < nkt - 1) asm volatile("s_waitcnt vmcnt(4)" ::: "memory");
    else              asm volatile("s_waitcnt vmcnt(0)" ::: "memory");
    __builtin_amdgcn_s_barrier();
    if (it + 2 < nkt) STAGEU(it + 2);
    int bi = it % 3;
    const ushort* ap = &As[0][0] + bi * 4096 + apo;
    const ushort* bp = &Bs[0][0] + bi * 4096 + bpo;
    short8 a[4], b[4];
#pragma unroll
    for (int i = 0; i < 4; ++i) a[i] = *(const short8*)(ap + i * 16 * 32);
#pragma unroll
    for (int j = 0; j < 4; ++j) b[j] = *(const short8*)(bp + j * 16 * 32);
#pragma unroll
    for (int i = 0; i < 4; ++i)
#pragma unroll
      for (int j = 0; j < 4; ++j)
        acc[i][j] = __builtin_amdgcn_mfma_f32_16x16x32_bf16(a[i], b[j], acc[i][j], 0, 0, 0);
  }
#undef STAGEU
  int ccol = lane & 15, crow = (lane >> 4) * 4;
#pragma unroll
  for (int i = 0; i < 4; ++i)
#pragma unroll
    for (int j = 0; j < 4; ++j) {
      int grow = m0 + wm * 64 + i * 16 + crow;
      int gcol = n0 + wn * 64 + j * 16 + ccol;
#pragma unroll
      for (int r = 0; r < 4; ++r)
        Cb[(size_t)(grow + r) * 2048 + gcol] = f2bf(acc[i][j][r]);
    }
}

// ---------------- fused qk|v GEMM, 4 waves x (64x64), 128x128 tile, ring-3, unrolled ------
__global__ __launch_bounds__(256) void k_gemm_qkv(const ushort* __restrict__ convb,
                                                  const ushort* __restrict__ upb,
                                                  const ushort* __restrict__ wt_qk,
                                                  const ushort* __restrict__ wt_v,
                                                  ushort* __restrict__ qkb,
                                                  ushort* __restrict__ vb,
                                                  ushort* __restrict__ vbt) {
  __shared__ ushort As[3][4096];
  __shared__ ushort Bs[3][4096];
  int tid = threadIdx.x;
  int wave = tid >> 6, lane = tid & 63;
  int wm = wave >> 1, wn = wave & 1;
  int bx, by; xcd_swz(&bx, &by);
  int isv = bx >= 16;
  int m0 = by * 128;
  int n0 = (isv ? bx - 16 : bx) * 128;
  const ushort* A = isv ? upb : convb;
  int lda = isv ? 2048 : 1024;
  const ushort* Bt = isv ? wt_v : wt_qk;
  int scol = swz_scol(lane);
  const ushort* Ag1 = A + (size_t)(m0 + wave * 32 + (lane >> 2)) * lda + scol;
  const ushort* Ag2 = Ag1 + (size_t)16 * lda;
  const ushort* Bg1 = Bt + (size_t)(n0 + wave * 32 + (lane >> 2)) * II + scol;
  const ushort* Bg2 = Bg1 + (size_t)16 * II;
  int woff = wave * 1024;
  int l15 = lane & 15, fk = swz_fk(lane);
  int apo = (wm * 64 + l15) * 32 + fk;
  int bpo = (wn * 64 + l15) * 32 + fk;
  f32x4 acc[4][4] = {};
  const int nkt = II / 32;
#define STAGEQ(p) { int kt_ = (p) * 32; int bi_ = (p) % 3; \
    async16(Ag1 + kt_, &As[0][0] + bi_ * 4096 + woff); \
    async16(Ag2 + kt_, &As[0][0] + bi_ * 4096 + woff + 512); \
    async16(Bg1 + kt_, &Bs[0][0] + bi_ * 4096 + woff); \
    async16(Bg2 + kt_, &Bs[0][0] + bi_ * 4096 + woff + 512); }
  STAGEQ(0);
  STAGEQ(1);
#pragma unroll
  for (int it = 0; it < nkt; ++it) {
    if (it < nkt - 1) asm volatile("s_waitcnt vmcnt(4)" ::: "memory");
    else              asm volatile("s_waitcnt vmcnt(0)" ::: "memory");
    __builtin_amdgcn_s_barrier();
    if (it + 2 < nkt) STAGEQ(it + 2);
    int bi = it % 3;
    const ushort* ap = &As[0][0] + bi * 4096 + apo;
    const ushort* bp = &Bs[0][0] + bi * 4096 + bpo;
    short8 a[4], b[4];
#pragma unroll
    for (int i = 0; i < 4; ++i) a[i] = *(const short8*)(ap + i * 16 * 32);
#pragma unroll
    for (int j = 0; j < 4; ++j) b[j] = *(const short8*)(bp + j * 16 * 32);
#pragma unroll
    for (int i = 0; i < 4; ++i)
#pragma unroll
      for (int j = 0; j < 4; ++j)
        acc[i][j] = __builtin_amdgcn_mfma_f32_16x16x32_bf16(a[i], b[j], acc[i][j], 0, 0, 0);
  }
#undef STAGEQ
  int ccol = lane & 15, crow = (lane >> 4) * 4;
#pragma unroll
  for (int i = 0; i < 4; ++i)
#pragma unroll
    for (int j = 0; j < 4; ++j) {
      int grow = m0 + wm * 64 + i * 16 + crow;
      int gcol = n0 + wn * 64 + j * 16 + ccol;
      if (!isv) {
#pragma unroll
        for (int r = 0; r < 4; ++r)
          qkb[(size_t)(grow + r) * 2048 + gcol] = f2bf(acc[i][j][r]);
      } else {
#pragma unroll
        for (int r = 0; r < 4; ++r)
          vb[(size_t)(grow + r) * II + gcol] = f2bf(acc[i][j][r]);
        int b8 = grow >> 9, sloc = grow & 511;
        int nh = gcol >> 7, d = gcol & 127;
        ushort4v o;
#pragma unroll
        for (int r = 0; r < 4; ++r) o[r] = f2bf(acc[i][j][r]);
        *(ushort4v*)&vbt[((size_t)(b8 * NHH + nh) * DHH + d) * SS + sloc] = o;
      }
    }
}

// ---------------- down GEMM: 4 waves x (64x64), split-K=4, atomic f32, unrolled (nkt=8) ---
__global__ __launch_bounds__(256) void k_gemm_down(const ushort* __restrict__ A,
                                                   const ushort* __restrict__ Bt,
                                                   float* __restrict__ Cf) {
  __shared__ ushort As[3][4096];
  __shared__ ushort Bs[3][4096];
  int tid = threadIdx.x;
  int wave = tid >> 6, lane = tid & 63;
  int wm = wave >> 1, wn = wave & 1;
  int bx, by; xcd_swz(&bx, &by);
  int m0 = by * 128, n0 = bx * 128;
  int k0 = blockIdx.z * 256;
  int scol = swz_scol(lane);
  const ushort* Ag1 = A + (size_t)(m0 + wave * 32 + (lane >> 2)) * II + k0 + scol;
  const ushort* Ag2 = Ag1 + (size_t)16 * II;
  const ushort* Bg1 = Bt + (size_t)(n0 + wave * 32 + (lane >> 2)) * II + k0 + scol;
  const ushort* Bg2 = Bg1 + (size_t)16 * II;
  int woff = wave * 1024;
  int l15 = lane & 15, fk = swz_fk(lane);
  int apo = (wm * 64 + l15) * 32 + fk;
  int bpo = (wn * 64 + l15) * 32 + fk;
  f32x4 acc[4][4] = {};
  const int nkt = 256 / 32;  // 8
#define STAGED(p) { int kt_ = (p) * 32; int bi_ = (p) % 3; \
    async16(Ag1 + kt_, &As[0][0] + bi_ * 4096 + woff); \
    async16(Ag2 + kt_, &As[0][0] + bi_ * 4096 + woff + 512); \
    async16(Bg1 + kt_, &Bs[0][0] + bi_ * 4096 + woff); \
    async16(Bg2 + kt_, &Bs[0][0] + bi_ * 4096 + woff + 512); }
  STAGED(0);
  STAGED(1);
#pragma unroll
  for (int it = 0; it < nkt; ++it) {
    if (it < nkt - 1) asm volatile("s_waitcnt vmcnt(4)" ::: "memory");
    else              asm volatile("s_waitcnt vmcnt(0)" ::: "memory");
    __builtin_amdgcn_s_barrier();
    if (it + 2 < nkt) STAGED(it + 2);
    int bi = it % 3;
    const ushort* ap = &As[0][0] + bi * 4096 + apo;
    const ushort* bp = &Bs[0][0] + bi * 4096 + bpo;
    short8 a[4], b[4];
#pragma unroll
    for (int i = 0; i < 4; ++i) a[i] = *(const short8*)(ap + i * 16 * 32);
#pragma unroll
    for (int j = 0; j < 4; ++j) b[j] = *(const short8*)(bp + j * 16 * 32);
#pragma unroll
    for (int i = 0; i < 4; ++i)
#pragma unroll
      for (int j = 0; j < 4; ++j)
        acc[i][j] = __builtin_amdgcn_mfma_f32_16x16x32_bf16(a[i], b[j], acc[i][j], 0, 0, 0);
  }
#undef STAGED
  int ccol = lane & 15, crow = (lane >> 4) * 4;
#pragma unroll
  for (int i = 0; i < 4; ++i)
#pragma unroll
    for (int j = 0; j < 4; ++j) {
      int grow = m0 + wm * 64 + i * 16 + crow;
      int gcol = n0 + wn * 64 + j * 16 + ccol;
#pragma unroll
      for (int r = 0; r < 4; ++r)
        atomicAdd(&Cf[(size_t)(grow + r) * DD + gcol], acc[i][j][r]);
    }
}

// ---------------- causal conv (K=4) + SiLU, 8 channels/thread ----------------
__global__ __launch_bounds__(256) void k_conv_silu(const ushort* __restrict__ up,
                                                   const float* __restrict__ cw,
                                                   const float* __restrict__ cb,
                                                   ushort* __restrict__ out) {
  int g = blockIdx.x * 256 + threadIdx.x;
  int c8 = (g & 127) * 8;
  int row = g >> 7;
  int s = row & (SS - 1);
  float acc[8];
  float4 wv[8];
#pragma unroll
  for (int t = 0; t < 8; ++t) {
    acc[t] = cb[c8 + t];
    wv[t] = *(const float4*)(cw + (size_t)(c8 + t) * 4);
  }
#pragma unroll
  for (int j = 0; j < 4; ++j) {
    int so = s + j - 3;
    if (so >= 0) {
      ushort8 u = *(const ushort8*)&up[(size_t)(row + j - 3) * 2048 + c8];
#pragma unroll
      for (int t = 0; t < 8; ++t) {
        float wc = (j == 0) ? wv[t].x : (j == 1) ? wv[t].y : (j == 2) ? wv[t].z : wv[t].w;
        acc[t] += bf2f(u[t]) * wc;
      }
    }
  }
  ushort8 o;
#pragma unroll
  for (int t = 0; t < 8; ++t) {
    float sig = 1.0f / (1.0f + __expf(-acc[t]));
    o[t] = f2bf(acc[t] * sig);
  }
  *(ushort8*)&out[(size_t)row * II + c8] = o;
}

// ---------------- gate projections via MFMA: 4 waves, K-split + LDS reduce ----------------
__global__ __launch_bounds__(256) void k_gates_mfma(const ushort* __restrict__ qkb,
                                                    const ushort* __restrict__ vb,
                                                    const ushort* __restrict__ Wg,
                                                    const float* __restrict__ igb,
                                                    const float* __restrict__ fgb,
                                                    float* __restrict__ ig,
                                                    float* __restrict__ fg) {
  int tid = threadIdx.x;
  int wave = tid >> 6, lane = tid & 63;
  int row0 = blockIdx.x * 16;
  int l15 = lane & 15, lg = lane >> 4;
  int arow = row0 + l15;
  const ushort* qrow = qkb + (size_t)arow * 2048 + lg * 8;
  const ushort* vrow = vb + (size_t)arow * II + lg * 8;
  const ushort* wrow = Wg + (size_t)l15 * (3 * II) + lg * 8;
  f32x4 acc0 = {}, acc1 = {};
#pragma unroll
  for (int i = 0; i < 12; ++i) {
    int off = (wave * 12 + i) * 64;
    const ushort* ab = (off < 2048) ? (qrow + off) : (vrow + (off - 2048));
    short8 a0 = *(const short8*)(ab);
    short8 b0 = *(const short8*)(wrow + off);
    short8 a1 = *(const short8*)(ab + 32);
    short8 b1 = *(const short8*)(wrow + off + 32);
    acc0 = __builtin_amdgcn_mfma_f32_16x16x32_bf16(a0, b0, acc0, 0, 0, 0);
    acc1 = __builtin_amdgcn_mfma_f32_16x16x32_bf16(a1, b1, acc1, 0, 0, 0);
  }
  __shared__ f32x4 red[4][64];
  f32x4 part;
#pragma unroll
  for (int r = 0; r < 4; ++r) part[r] = acc0[r] + acc1[r];
  red[wave][lane] = part;
  __syncthreads();
  if (wave == 0) {
    f32x4 t0 = red[0][lane], t1 = red[1][lane], t2 = red[2][lane], t3 = red[3][lane];
    int o = l15;
#pragma unroll
    for (int r = 0; r < 4; ++r) {
      int row = row0 + lg * 4 + r;
      int bb = row >> 9, s = row & (SS - 1);
      float val = t0[r] + t1[r] + t2[r] + t3[r];
      if (o < NHH)
        ig[((size_t)bb * NHH + o) * SS + s] = val + igb[o];
      else
        fg[((size_t)bb * NHH + (o - NHH)) * SS + s] = val + fgb[o - NHH];
    }
  }
}

// ---------------- per-(b,n) scan: one wave per bn, shfl prefix ----------------
__global__ __launch_bounds__(64) void k_scan(const float* __restrict__ ig,
                                             const float* __restrict__ fg,
                                             float* __restrict__ e_g, float* __restrict__ M_g,
                                             float* __restrict__ maxd_g) {
  int bn = blockIdx.x;
  int lane = threadIdx.x;
  size_t base = (size_t)bn * SS + lane * 8;
  float4 f0 = *(const float4*)&fg[base];
  float4 f1 = *(const float4*)&fg[base + 4];
  float fv[8] = {f0.x, f0.y, f0.z, f0.w, f1.x, f1.y, f1.z, f1.w};
  float lf[8];
#pragma unroll
  for (int j = 0; j < 8; ++j) {
    float f = fv[j];
    lf[j] = (f >= 0.f) ? -log1pf(expf(-f)) : (f - log1pf(expf(f)));
  }
  float cum[8];
  float run = 0.f;
#pragma unroll
  for (int j = 0; j < 8; ++j) { run += lf[j]; cum[j] = run; }
  float inc = run;
#pragma unroll
  for (int off = 1; off < 64; off <<= 1) {
    float t = __shfl_up(inc, off);
    if (lane >= off) inc += t;
  }
  float exs = inc - run;
  float4 i0 = *(const float4*)&ig[base];
  float4 i1 = *(const float4*)&ig[base + 4];
  float igv[8] = {i0.x, i0.y, i0.z, i0.w, i1.x, i1.y, i1.z, i1.w};
  float cs[8], e[8];
#pragma unroll
  for (int j = 0; j < 8; ++j) {
    cs[j] = exs + cum[j];
    e[j] = igv[j] - cs[j];
  }
  float mcum[8];
  float mrun = -3.0e38f;
#pragma unroll
  for (int j = 0; j < 8; ++j) { mrun = fmaxf(mrun, e[j]); mcum[j] = mrun; }
  float minc = mrun;
#pragma unroll
  for (int off = 1; off < 64; off <<= 1) {
    float t = __shfl_up(minc, off);
    if (lane >= off) minc = fmaxf(minc, t);
  }
  float mex = __shfl_up(minc, 1);
  if (lane == 0) mex = -3.0e38f;
  float M[8], mdv[8];
#pragma unroll
  for (int j = 0; j < 8; ++j) {
    M[j] = fmaxf(mex, mcum[j]);
    mdv[j] = cs[j] + M[j];
  }
  *(float4*)&e_g[base] = make_float4(e[0], e[1], e[2], e[3]);
  *(float4*)&e_g[base + 4] = make_float4(e[4], e[5], e[6], e[7]);
  *(float4*)&M_g[base] = make_float4(M[0], M[1], M[2], M[3]);
  *(float4*)&M_g[base + 4] = make_float4(M[4], M[5], M[6], M[7]);
  *(float4*)&maxd_g[base] = make_float4(mdv[0], mdv[1], mdv[2], mdv[3]);
  *(float4*)&maxd_g[base + 4] = make_float4(mdv[4], mdv[5], mdv[6], mdv[7]);
}

// ---------------- mLSTM attention, MFMA bf16, async dbuf staging, fused GN epilogue --------
__global__ __launch_bounds__(256) void k_attn_mfma(const ushort* __restrict__ qkb,
                                                   const ushort* __restrict__ vbt,
                                                   const float* __restrict__ e_g,
                                                   const float* __restrict__ M_g,
                                                   const float* __restrict__ maxd_g,
                                                   const ushort* __restrict__ convact,
                                                   const ushort* __restrict__ up,
                                                   const float* __restrict__ gnw,
                                                   const float* __restrict__ skw,
                                                   ushort* __restrict__ hs) {
  __shared__ __align__(16) ushort K2[2][64 * 128];
  __shared__ __align__(16) ushort V2[2][128 * 64];
  __shared__ __align__(16) ushort w_s[4][16 * 72];
  __shared__ float e_s[SS];

  int tid = threadIdx.x;
  int wave = tid >> 6, lane = tid & 63;
  int xb = blockIdx.x;
  int stile = (xb & 1) ? (7 - (xb >> 1)) : (xb >> 1);
  int bn = blockIdx.y;
  int b = bn >> 3, n = bn & 7;
  int s0 = stile * 64;

  const size_t qbase = (size_t)(b * SS) * 2048 + (size_t)n * DHH;
  const size_t kbase = qbase + II;
  const size_t vtbase = (size_t)bn * DHH * SS;

  int l15 = lane & 15, lg = lane >> 4;
  int kg8 = lg * 8;
  int crow = lg * 4;
  int srow_base = s0 + wave * 16 + crow;

  e_s[tid] = e_g[(size_t)bn * SS + tid];
  e_s[tid + 256] = e_g[(size_t)bn * SS + tid + 256];

  short8 qf[4];
  {
    int qrow = s0 + wave * 16 + l15;
#pragma unroll
    for (int ks = 0; ks < 4; ++ks)
      qf[ks] = *(const short8*)&qkb[qbase + (size_t)qrow * 2048 + ks * 32 + kg8];
  }
  float Ms[4], md[4];
#pragma unroll
  for (int r = 0; r < 4; ++r) {
    Ms[r] = M_g[(size_t)bn * SS + srow_base + r];
    md[r] = maxd_g[(size_t)bn * SS + srow_base + r];
  }

  f32x4 acc[8] = {};
  float rsum[4] = {};
  const float rsq = 0.08838834764831845f;
  ushort* w_w = &w_s[wave][0];
  int ntt = stile + 1;

#pragma unroll
  for (int i = 0; i < 4; ++i) {
    int r = wave * 16 + i * 4 + (lane >> 4);
    int sp = (lane & 15) ^ (r & 7);
    async16(&qkb[kbase + (size_t)r * 2048 + sp * 8], &K2[0][(wave * 16 + i * 4) * 128]);
  }
#pragma unroll
  for (int i = 0; i < 4; ++i) {
    int d = wave * 32 + i * 8 + (lane >> 3);
    int sp = (lane & 7) ^ (d & 7);
    async16(&vbt[vtbase + (size_t)d * SS + sp * 8], &V2[0][(wave * 32 + i * 8) * 64]);
  }

  for (int tt = 0; tt < ntt; ++tt) {
    int cur = tt & 1;
    if (tt + 1 < ntt) {
      int t1 = (tt + 1) * 64;
      int nxt = cur ^ 1;
#pragma unroll
      for (int i = 0; i < 4; ++i) {
        int r = wave * 16 + i * 4 + (lane >> 4);
        int sp = (lane & 15) ^ (r & 7);
        async16(&qkb[kbase + (size_t)(t1 + r) * 2048 + sp * 8], &K2[nxt][(wave * 16 + i * 4) * 128]);
      }
#pragma unroll
      for (int i = 0; i < 4; ++i) {
        int d = wave * 32 + i * 8 + (lane >> 3);
        int sp = (lane & 7) ^ (d & 7);
        async16(&vbt[vtbase + (size_t)d * SS + t1 + sp * 8], &V2[nxt][(wave * 32 + i * 8) * 64]);
      }
      asm volatile("s_waitcnt vmcnt(8) lgkmcnt(0)" ::: "memory");
    } else {
      asm volatile("s_waitcnt vmcnt(0) lgkmcnt(0)" ::: "memory");
    }
    __builtin_amdgcn_s_barrier();

    int t0 = tt * 64;
    const ushort* Kc = &K2[cur][0];
    const ushort* Vc = &V2[cur][0];

    f32x4 s4[4];
#pragma unroll
    for (int ct = 0; ct < 4; ++ct) {
      f32x4 c = {};
      int ro = l15 + 16 * ct;
#pragma unroll
      for (int ks = 0; ks < 4; ++ks) {
        int sp = (ks * 4 + lg) ^ (ro & 7);
        short8 kf = *(const short8*)&Kc[ro * 128 + sp * 8];
        c = __builtin_amdgcn_mfma_f32_16x16x32_bf16(qf[ks], kf, c, 0, 0, 0);
      }
      s4[ct] = c;
    }
#pragma unroll
    for (int ct = 0; ct < 4; ++ct) {
      int t = t0 + l15 + 16 * ct;
      float e = e_s[t];
#pragma unroll
      for (int r = 0; r < 4; ++r) {
        int s = srow_base + r;
        float val = (t <= s) ? s4[ct][r] * rsq * __expf(e - Ms[r]) : 0.f;
        s4[ct][r] = val;
        w_w[(crow + r) * 72 + l15 + 16 * ct] = f2bf(val);
      }
    }
#pragma unroll
    for (int r = 0; r < 4; ++r) {
      float tmp = s4[0][r] + s4[1][r] + s4[2][r] + s4[3][r];
      tmp += __shfl_xor(tmp, 1);
      tmp += __shfl_xor(tmp, 2);
      tmp += __shfl_xor(tmp, 4);
      tmp += __shfl_xor(tmp, 8);
      rsum[r] += tmp;
    }
    short8 wf0 = *(const short8*)&w_w[l15 * 72 + kg8];
    short8 wf1 = *(const short8*)&w_w[l15 * 72 + 32 + kg8];
#pragma unroll
    for (int dt = 0; dt < 8; ++dt) {
      int d = dt * 16 + l15;
      int sp0 = lg ^ (d & 7);
      int sp1 = (lg + 4) ^ (d & 7);
      short8 vf0 = *(const short8*)&Vc[d * 64 + sp0 * 8];
      short8 vf1 = *(const short8*)&Vc[d * 64 + sp1 * 8];
      acc[dt] = __builtin_amdgcn_mfma_f32_16x16x32_bf16(wf0, vf0, acc[dt], 0, 0, 0);
      acc[dt] = __builtin_amdgcn_mfma_f32_16x16x32_bf16(wf1, vf1, acc[dt], 0, 0, 0);
    }
    __builtin_amdgcn_s_barrier();
  }

  float scl[4], sum[4] = {}, sq[4] = {};
#pragma unroll
  for (int r = 0; r < 4; ++r) {
    float nrm = fmaxf(fabsf(rsum[r]), __expf(-md[r]));
    scl[r] = 1.0f / (nrm + 1e-6f);
  }
#pragma unroll
  for (int dt = 0; dt < 8; ++dt)
#pragma unroll
    for (int r = 0; r < 4; ++r) {
      float v = acc[dt][r] * scl[r];
      sum[r] += v;
      sq[r] += v * v;
    }
#pragma unroll
  for (int r = 0; r < 4; ++r) {
#pragma unroll
    for (int off = 1; off <= 8; off <<= 1) {
      sum[r] += __shfl_xor(sum[r], off);
      sq[r] += __shfl_xor(sq[r], off);
    }
  }
  float mu[4], rstd[4];
#pragma unroll
  for (int r = 0; r < 4; ++r) {
    mu[r] = sum[r] * (1.0f / DHH);
    float var = sq[r] * (1.0f / DHH) - mu[r] * mu[r];
    rstd[r] = rsqrtf(var + 1e-5f);
  }
#pragma unroll
  for (int dt = 0; dt < 8; ++dt) {
    int c = dt * 16 + l15;
    float gw = gnw[n * DHH + c];
    float sw = skw[n * DHH + c];
#pragma unroll
    for (int r = 0; r < 4; ++r) {
      size_t ridx = (size_t)(b * SS + srow_base + r);
      float v = acc[dt][r] * scl[r];
      float hn = (v - mu[r]) * rstd[r] * gw;
      float ca = bf2f(convact[ridx * II + n * DHH + c]);
      float z = bf2f(up[ridx * 2048 + II + n * DHH + c]);
      float sz = z / (1.0f + __expf(-z));
      hs[ridx * II + n * DHH + c] = f2bf((hn + sw * ca) * sz);
    }
  }
}

// ---------------- final LN(last row) + 2-layer head ----------------
__global__ __launch_bounds__(256) void k_head(const float* __restrict__ h,
                                              const float* __restrict__ pw,
                                              const float* __restrict__ pb,
                                              const float* __restrict__ w1,
                                              const float* __restrict__ b1,
                                              const float* __restrict__ w2,
                                              const float* __restrict__ b2,
                                              float* __restrict__ out) {
  int b = blockIdx.x;
  int tid = threadIdx.x;
  __shared__ float last[DD];
  __shared__ float hid[H1H];
  __shared__ float ss[4], sqs[4];
  const float* row = h + ((size_t)b * SS + SS - 1) * DD;
  float v0 = row[tid], v1 = row[tid + 256];
  float s = v0 + v1, sq = v0 * v0 + v1 * v1;
  for (int off = 32; off; off >>= 1) {
    s += __shfl_down(s, off);
    sq += __shfl_down(sq, off);
  }
  int wid = tid >> 6, lane = tid & 63;
  if (lane == 0) { ss[wid] = s; sqs[wid] = sq; }
  __syncthreads();
  if (tid == 0) {
    ss[0] = ss[0] + ss[1] + ss[2] + ss[3];
    sqs[0] = sqs[0] + sqs[1] + sqs[2] + sqs[3];
  }
  __syncthreads();
  float mean = ss[0] * (1.0f / DD);
  float var = sqs[0] * (1.0f / DD) - mean * mean;
  float r = rsqrtf(var + 1e-5f);
  last[tid] = (v0 - mean) * r * pw[tid] + pb[tid];
  last[tid + 256] = (v1 - mean) * r * pw[tid + 256] + pb[tid + 256];
  __syncthreads();
  if (tid < H1H) {
    float a = b1[tid];
    for (int d2 = 0; d2 < DD; ++d2) a += last[d2] * w1[(size_t)d2 * H1H + tid];
    hid[tid] = fmaxf(a, 0.f);
  }
  __syncthreads();
  if (tid < OUTO) {
    float a = b2[tid];
#pragma unroll
    for (int j2 = 0; j2 < H1H; ++j2) a += hid[j2] * w2[(size_t)j2 * OUTO + tid];
    out[(size_t)b * OUTO + tid] = a;
  }
}

extern "C" void kernel_launch(void* const* d_in, const int* in_sizes, int n_in,
                              void* d_out, int out_size, void* d_ws, size_t ws_size,
                              hipStream_t stream) {
  (void)in_sizes; (void)n_in; (void)out_size; (void)ws_size;
  const float* x    = (const float*)d_in[0];
  const float* in_w = (const float*)d_in[1];
  const float* in_b = (const float*)d_in[2];
  const float* ln_w = (const float*)d_in[3];
  const float* ln_b = (const float*)d_in[4];
  const float* up_w = (const float*)d_in[5];
  const float* conv_w = (const float*)d_in[6];
  const float* conv_b = (const float*)d_in[7];
  const float* q_w  = (const float*)d_in[8];
  const float* k_w  = (const float*)d_in[9];
  const float* v_w  = (const float*)d_in[10];
  const float* ig_w = (const float*)d_in[11];
  const float* ig_b = (const float*)d_in[12];
  const float* fg_w = (const float*)d_in[13];
  const float* fg_b = (const float*)d_in[14];
  const float* gn_w = (const float*)d_in[15];
  const float* sk_w = (const float*)d_in[16];
  const float* dn_w = (const float*)d_in[17];
  const float* po_w = (const float*)d_in[18];
  const float* po_b = (const float*)d_in[19];
  const float* h1_w = (const float*)d_in[20];
  const float* h1_b = (const float*)d_in[21];
  const float* h2_w = (const float*)d_in[22];
  const float* h2_b = (const float*)d_in[23];

  float* h = (float*)d_ws;                              // 2M f32
  ushort* xn_bf = (ushort*)(h + 2097152);               // 2M bf16
  ushort* up_bf = xn_bf + 2097152;                      // 8M
  ushort* conv_bf = up_bf + 8388608;                    // 4M
  ushort* qkb = conv_bf + 4194304;                      // 8M (q | k fused)
  ushort* vb = qkb + 8388608;                           // 4M
  ushort* vbt = vb + 4194304;                           // 4M (per-head V^T)
  ushort* hs_bf = vbt + 4194304;                        // 4M
  ushort* wt_up = hs_bf + 4194304;                      // 2 x 1M
  ushort* wt_qk = wt_up + 2097152;                      // 2 x 2M
  ushort* wt_v  = wt_qk + 4194304;                      // 2 x 1M
  ushort* wt_dn = wt_v + 2097152;                       // 2 x 0.5M
  ushort* Wg = wt_dn + 1048576;                         // 2 x 49152
  float* igb_ = (float*)(Wg + 98304);
  float* fgb_ = igb_ + 32768;
  float* e_g  = fgb_ + 32768;
  float* M_g  = e_g + 32768;
  float* md_g = M_g + 32768;

  k_pre<<<2584, 256, 0, stream>>>(x, in_w, in_b, ln_w, ln_b, h, xn_bf,
                                  up_w, q_w, k_w, v_w, dn_w, ig_w, fg_w,
                                  wt_up, wt_qk, wt_v, wt_dn, Wg);
  for (int l = 0; l < 2; ++l) {
    if (l) k_layernorm<<<BS, 256, 0, stream>>>(h, ln_w + l * DD, ln_b + l * DD, xn_bf);
    k_gemm_up<<<dim3(16, 32), 256, 0, stream>>>(xn_bf, wt_up + (size_t)l * 1048576, up_bf);
    k_conv_silu<<<BS * II / 8 / 256, 256, 0, stream>>>(up_bf, conv_w + l * II * KK,
                                                       conv_b + l * II, conv_bf);
    k_gemm_qkv<<<dim3(24, 32), 256, 0, stream>>>(conv_bf, up_bf,
                                                 wt_qk + (size_t)l * 2097152,
                                                 wt_v + (size_t)l * 1048576,
                                                 qkb, vb, vbt);
    k_gates_mfma<<<256, 256, 0, stream>>>(qkb, vb, Wg + (size_t)l * 49152,
                                          ig_b + l * NHH, fg_b + l * NHH, igb_, fgb_);
    k_scan<<<BB * NHH, 64, 0, stream>>>(igb_, fgb_, e_g, M_g, md_g);
    k_attn_mfma<<<dim3(8, BB * NHH), 256, 0, stream>>>(qkb, vbt, e_g, M_g, md_g,
                                                       conv_bf, up_bf,
                                                       gn_w + l * II, sk_w + l * II, hs_bf);
    k_gemm_down<<<dim3(4, 32, 4), 256, 0, stream>>>(hs_bf, wt_dn + (size_t)l * 524288, h);
  }
  k_head<<<BB, 256, 0, stream>>>(h, po_w, po_b, h1_w, h1_b, h2_w, h2_b, (float*)d_out);
}

// Round 21
// 331.689 us; speedup vs baseline: 1.0081x; 1.0081x over previous
//
#include <hip/hip_runtime.h>
#include <math.h>

#define BB 8
#define SS 512
#define FF 64
#define DD 512
#define II 1024
#define NHH 8
#define KK 4
#define DHH 128
#define H1H 32
#define OUTO 24
#define BS (BB*SS)   // 4096

typedef unsigned short ushort;
typedef __attribute__((ext_vector_type(8))) short short8;
typedef __attribute__((ext_vector_type(8))) unsigned short ushort8;
typedef __attribute__((ext_vector_type(4))) unsigned short ushort4v;
typedef __attribute__((ext_vector_type(4))) float f32x4;

__device__ __forceinline__ float bf2f(ushort u) {
  return __uint_as_float(((unsigned int)u) << 16);
}
__device__ __forceinline__ ushort f2bf(float f) {
  unsigned int u = __float_as_uint(f);
  unsigned int r = u + 0x7fffu + ((u >> 16) & 1u);
  return (ushort)(r >> 16);
}

typedef __attribute__((address_space(1))) const void gvoid;
typedef __attribute__((address_space(3))) void lvoid;
__device__ __forceinline__ void async16(const void* g, void* l) {
  __builtin_amdgcn_global_load_lds((gvoid*)g, (lvoid*)l, 16, 0, 0);
}

// ---------------- fused prologue ----------------
// blocks 0..255: input proj + layer-0 LN (16 rows each)
// blocks 256..2583: weight transpose 64x64 tiles + gate pack, both layers
__global__ __launch_bounds__(256) void k_pre(const float* __restrict__ x,
                                             const float* __restrict__ w,
                                             const float* __restrict__ b,
                                             const float* __restrict__ lnw,
                                             const float* __restrict__ lnb,
                                             float* __restrict__ h,
                                             ushort* __restrict__ xn,
                                             const float* __restrict__ up_w,
                                             const float* __restrict__ q_w,
                                             const float* __restrict__ k_w,
                                             const float* __restrict__ v_w,
                                             const float* __restrict__ dn_w,
                                             const float* __restrict__ igw,
                                             const float* __restrict__ fgw,
                                             ushort* __restrict__ wt_up,
                                             ushort* __restrict__ wt_qk,
                                             ushort* __restrict__ wt_v,
                                             ushort* __restrict__ wt_dn,
                                             ushort* __restrict__ Wg) {
  int blk0 = blockIdx.x;
  int tid = threadIdx.x;
  if (blk0 < 256) {
    int r0 = blk0 * 16;
    __shared__ float xs[16][FF];
    for (int i = tid; i < 16 * FF; i += 256)
      xs[i >> 6][i & 63] = x[(size_t)(r0 + (i >> 6)) * FF + (i & 63)];
    __syncthreads();
    float acc0[16], acc1[16];
    float b0 = b[tid], b1 = b[tid + 256];
#pragma unroll
    for (int r = 0; r < 16; ++r) { acc0[r] = b0; acc1[r] = b1; }
    for (int f = 0; f < FF; ++f) {
      float w0 = w[(size_t)f * DD + tid];
      float w1 = w[(size_t)f * DD + tid + 256];
#pragma unroll
      for (int r = 0; r < 16; ++r) {
        float xv = xs[r][f];
        acc0[r] += xv * w0;
        acc1[r] += xv * w1;
      }
    }
#pragma unroll
    for (int r = 0; r < 16; ++r) {
      h[(size_t)(r0 + r) * DD + tid] = acc0[r];
      h[(size_t)(r0 + r) * DD + tid + 256] = acc1[r];
    }
    float s[16], q[16];
#pragma unroll
    for (int r = 0; r < 16; ++r) {
      s[r] = acc0[r] + acc1[r];
      q[r] = acc0[r] * acc0[r] + acc1[r] * acc1[r];
    }
#pragma unroll
    for (int off = 32; off; off >>= 1) {
#pragma unroll
      for (int r = 0; r < 16; ++r) {
        s[r] += __shfl_down(s[r], off);
        q[r] += __shfl_down(q[r], off);
      }
    }
    __shared__ float ssum[4][16], ssq[4][16];
    int wid = tid >> 6, lane = tid & 63;
    if (lane == 0) {
#pragma unroll
      for (int r = 0; r < 16; ++r) { ssum[wid][r] = s[r]; ssq[wid][r] = q[r]; }
    }
    __syncthreads();
    __shared__ float smean[16], srstd[16];
    if (tid < 16) {
      float ts = ssum[0][tid] + ssum[1][tid] + ssum[2][tid] + ssum[3][tid];
      float tq = ssq[0][tid] + ssq[1][tid] + ssq[2][tid] + ssq[3][tid];
      float mean = ts * (1.0f / DD);
      float var = tq * (1.0f / DD) - mean * mean;
      smean[tid] = mean;
      srstd[tid] = rsqrtf(var + 1e-5f);
    }
    __syncthreads();
    float w0 = lnw[tid], w1 = lnw[tid + 256];
    float bb0 = lnb[tid], bb1 = lnb[tid + 256];
#pragma unroll
    for (int r = 0; r < 16; ++r) {
      float mean = smean[r], rstd = srstd[r];
      xn[(size_t)(r0 + r) * DD + tid] = f2bf((acc0[r] - mean) * rstd * w0 + bb0);
      xn[(size_t)(r0 + r) * DD + tid + 256] = f2bf((acc1[r] - mean) * rstd * w1 + bb1);
    }
    return;
  }
  int blk = blk0 - 256;
  int l = blk / 1164;
  blk -= l * 1164;
  if (blk >= 1152) {
    const float* igwl = igw + (size_t)l * 3 * II * NHH;
    const float* fgwl = fgw + (size_t)l * 3 * II * NHH;
    ushort* Wgl = Wg + (size_t)l * 16 * 3 * II;
    int k = (blk - 1152) * 256 + tid;
    if (k < 3 * II) {
#pragma unroll
      for (int o = 0; o < NHH; ++o) {
        Wgl[(size_t)o * (3 * II) + k] = f2bf(igwl[(size_t)k * NHH + o]);
        Wgl[(size_t)(NHH + o) * (3 * II) + k] = f2bf(fgwl[(size_t)k * NHH + o]);
      }
    }
    return;
  }
  const float* src; ushort* dst; int N, Kd, t;
  if (blk < 256)       { src = up_w + (size_t)l * DD * 2 * II; dst = wt_up + (size_t)l * 1048576; N = 2048; Kd = 512;  t = blk; }
  else if (blk < 512)  { src = q_w + (size_t)l * II * II;  dst = wt_qk + (size_t)l * 2097152; N = 1024; Kd = 1024; t = blk - 256; }
  else if (blk < 768)  { src = k_w + (size_t)l * II * II;  dst = wt_qk + (size_t)l * 2097152 + 1024 * 1024; N = 1024; Kd = 1024; t = blk - 512; }
  else if (blk < 1024) { src = v_w + (size_t)l * II * II;  dst = wt_v + (size_t)l * 1048576;  N = 1024; Kd = 1024; t = blk - 768; }
  else                 { src = dn_w + (size_t)l * II * DD; dst = wt_dn + (size_t)l * 524288;  N = 512;  Kd = 1024; t = blk - 1024; }
  int ntn = N >> 6;
  int n0 = (t % ntn) * 64, k0 = (t / ntn) * 64;
  __shared__ float tb[64][65];
  int c4 = (tid & 15) * 4, r16 = tid >> 4;
#pragma unroll
  for (int p = 0; p < 4; ++p) {
    int row = r16 + p * 16;
    float4 v = *(const float4*)&src[(size_t)(k0 + row) * N + n0 + c4];
    tb[row][c4 + 0] = v.x;
    tb[row][c4 + 1] = v.y;
    tb[row][c4 + 2] = v.z;
    tb[row][c4 + 3] = v.w;
  }
  __syncthreads();
#pragma unroll
  for (int p = 0; p < 4; ++p) {
    int nrow = r16 + p * 16;
    ushort4v o;
#pragma unroll
    for (int j = 0; j < 4; ++j) o[j] = f2bf(tb[c4 + j][nrow]);
    *(ushort4v*)&dst[(size_t)(n0 + nrow) * Kd + k0 + c4] = o;
  }
}

// ---------------- row layernorm over D=512 -> bf16 out ----------------
__global__ __launch_bounds__(256) void k_layernorm(const float* __restrict__ in,
                                                   const float* __restrict__ w,
                                                   const float* __restrict__ b,
                                                   ushort* __restrict__ out) {
  int row = blockIdx.x;
  int tid = threadIdx.x;
  float v0 = in[(size_t)row * DD + tid];
  float v1 = in[(size_t)row * DD + tid + 256];
  float s = v0 + v1, sq = v0 * v0 + v1 * v1;
  for (int off = 32; off; off >>= 1) {
    s += __shfl_down(s, off);
    sq += __shfl_down(sq, off);
  }
  __shared__ float ss[4], sqs[4];
  int wid = tid >> 6, lane = tid & 63;
  if (lane == 0) { ss[wid] = s; sqs[wid] = sq; }
  __syncthreads();
  if (tid == 0) {
    ss[0] = ss[0] + ss[1] + ss[2] + ss[3];
    sqs[0] = sqs[0] + sqs[1] + sqs[2] + sqs[3];
  }
  __syncthreads();
  float mean = ss[0] * (1.0f / DD);
  float var = sqs[0] * (1.0f / DD) - mean * mean;
  float r = rsqrtf(var + 1e-5f);
  out[(size_t)row * DD + tid] = f2bf((v0 - mean) * r * w[tid] + b[tid]);
  out[(size_t)row * DD + tid + 256] = f2bf((v1 - mean) * r * w[tid + 256] + b[tid + 256]);
}

// ---------------- 8-wave GEMM core (32x64 wave tile), ring-3 (48KB), counted vmcnt --------
__device__ __forceinline__ void gemm_core8(const ushort* __restrict__ Ag,
                                           const ushort* __restrict__ Bg,
                                           int nkt, ushort* AsB, ushort* BsB,
                                           int woff, int apo, int bpo,
                                           f32x4 (&acc)[2][4]) {
#define STAGE8(p) { int kt_ = (p) * 32; int bi_ = (p) % 3; \
    async16(Ag + kt_, AsB + bi_ * 4096 + woff); \
    async16(Bg + kt_, BsB + bi_ * 4096 + woff); }
  if (0 < nkt) STAGE8(0);
  if (1 < nkt) STAGE8(1);
#pragma unroll
  for (int it = 0; it < nkt; ++it) {
    if (it < nkt - 1) asm volatile("s_waitcnt vmcnt(2)" ::: "memory");
    else              asm volatile("s_waitcnt vmcnt(0)" ::: "memory");
    __builtin_amdgcn_s_barrier();
    if (it + 2 < nkt) STAGE8(it + 2);
    int bi = it % 3;
    const ushort* ap = AsB + bi * 4096 + apo;
    const ushort* bp = BsB + bi * 4096 + bpo;
    short8 a[2], b[4];
#pragma unroll
    for (int i = 0; i < 2; ++i) a[i] = *(const short8*)(ap + i * 16 * 32);
#pragma unroll
    for (int j = 0; j < 4; ++j) b[j] = *(const short8*)(bp + j * 16 * 32);
#pragma unroll
    for (int i = 0; i < 2; ++i)
#pragma unroll
      for (int j = 0; j < 4; ++j)
        acc[i][j] = __builtin_amdgcn_mfma_f32_16x16x32_bf16(a[i], b[j], acc[i][j], 0, 0, 0);
  }
#undef STAGE8
}

// swizzle helpers (per-thread constants)
__device__ __forceinline__ int swz_scol(int lane) {
  return (((lane & 3) ^ ((lane >> 3) & 3)) * 8);
}
__device__ __forceinline__ int swz_fk(int lane) {
  return ((((lane >> 4) ^ (lane >> 1)) & 3) * 8);
}
__device__ __forceinline__ void xcd_swz(int* bx, int* by) {
  int gx = gridDim.x;
  int nwg = gx * gridDim.y;
  int orig = blockIdx.y * gx + blockIdx.x;
  int q = nwg >> 3;
  int wgid = (orig & 7) * q + (orig >> 3);
  *bx = wgid % gx;
  *by = wgid / gx;
}

// ---------------- up GEMM: up = xn @ wt_up^T  (K=512, N=2048, bf16 out), 8-wave core ------
__global__ __launch_bounds__(512) void k_gemm_up(const ushort* __restrict__ A,
                                                 const ushort* __restrict__ Bt,
                                                 ushort* __restrict__ Cb) {
  __shared__ ushort As[3][4096];
  __shared__ ushort Bs[3][4096];
  int tid = threadIdx.x;
  int wave = tid >> 6, lane = tid & 63;
  int wm = wave >> 1, wn = wave & 1;
  int bx, by; xcd_swz(&bx, &by);
  int m0 = by * 128, n0 = bx * 128;
  int srow = wave * 16 + (lane >> 2), scol = swz_scol(lane);
  const ushort* Ag = A + (size_t)(m0 + srow) * DD + scol;
  const ushort* Bg = Bt + (size_t)(n0 + srow) * DD + scol;
  int woff = wave * 512;
  int frow = lane & 15, fk = swz_fk(lane);
  int apo = (wm * 32 + frow) * 32 + fk;
  int bpo = (wn * 64 + frow) * 32 + fk;
  f32x4 acc[2][4] = {};
  gemm_core8(Ag, Bg, DD / 32, &As[0][0], &Bs[0][0], woff, apo, bpo, acc);
  int ccol = lane & 15, crow = (lane >> 4) * 4;
#pragma unroll
  for (int i = 0; i < 2; ++i)
#pragma unroll
    for (int j = 0; j < 4; ++j) {
      int grow = m0 + wm * 32 + i * 16 + crow;
      int gcol = n0 + wn * 64 + j * 16 + ccol;
#pragma unroll
      for (int r = 0; r < 4; ++r)
        Cb[(size_t)(grow + r) * 2048 + gcol] = f2bf(acc[i][j][r]);
    }
}

// ---------------- fused qk|v GEMM, 4 waves x (64x64), 128x128 tile, ring-3, unrolled ------
__global__ __launch_bounds__(256) void k_gemm_qkv(const ushort* __restrict__ convb,
                                                  const ushort* __restrict__ upb,
                                                  const ushort* __restrict__ wt_qk,
                                                  const ushort* __restrict__ wt_v,
                                                  ushort* __restrict__ qkb,
                                                  ushort* __restrict__ vb,
                                                  ushort* __restrict__ vbt) {
  __shared__ ushort As[3][4096];
  __shared__ ushort Bs[3][4096];
  int tid = threadIdx.x;
  int wave = tid >> 6, lane = tid & 63;
  int wm = wave >> 1, wn = wave & 1;
  int bx, by; xcd_swz(&bx, &by);
  int isv = bx >= 16;
  int m0 = by * 128;
  int n0 = (isv ? bx - 16 : bx) * 128;
  const ushort* A = isv ? upb : convb;
  int lda = isv ? 2048 : 1024;
  const ushort* Bt = isv ? wt_v : wt_qk;
  int scol = swz_scol(lane);
  const ushort* Ag1 = A + (size_t)(m0 + wave * 32 + (lane >> 2)) * lda + scol;
  const ushort* Ag2 = Ag1 + (size_t)16 * lda;
  const ushort* Bg1 = Bt + (size_t)(n0 + wave * 32 + (lane >> 2)) * II + scol;
  const ushort* Bg2 = Bg1 + (size_t)16 * II;
  int woff = wave * 1024;
  int frow = lane & 15, fk = swz_fk(lane);
  int apo = (wm * 64 + frow) * 32 + fk;
  int bpo = (wn * 64 + frow) * 32 + fk;
  f32x4 acc[4][4] = {};
  const int nkt = II / 32;
#define STAGEQ(p) { int kt_ = (p) * 32; int bi_ = (p) % 3; \
    async16(Ag1 + kt_, &As[0][0] + bi_ * 4096 + woff); \
    async16(Ag2 + kt_, &As[0][0] + bi_ * 4096 + woff + 512); \
    async16(Bg1 + kt_, &Bs[0][0] + bi_ * 4096 + woff); \
    async16(Bg2 + kt_, &Bs[0][0] + bi_ * 4096 + woff + 512); }
  STAGEQ(0);
  STAGEQ(1);
#pragma unroll
  for (int it = 0; it < nkt; ++it) {
    if (it < nkt - 1) asm volatile("s_waitcnt vmcnt(4)" ::: "memory");
    else              asm volatile("s_waitcnt vmcnt(0)" ::: "memory");
    __builtin_amdgcn_s_barrier();
    if (it + 2 < nkt) STAGEQ(it + 2);
    int bi = it % 3;
    const ushort* ap = &As[0][0] + bi * 4096 + apo;
    const ushort* bp = &Bs[0][0] + bi * 4096 + bpo;
    short8 a[4], b[4];
#pragma unroll
    for (int i = 0; i < 4; ++i) a[i] = *(const short8*)(ap + i * 16 * 32);
#pragma unroll
    for (int j = 0; j < 4; ++j) b[j] = *(const short8*)(bp + j * 16 * 32);
#pragma unroll
    for (int i = 0; i < 4; ++i)
#pragma unroll
      for (int j = 0; j < 4; ++j)
        acc[i][j] = __builtin_amdgcn_mfma_f32_16x16x32_bf16(a[i], b[j], acc[i][j], 0, 0, 0);
  }
#undef STAGEQ
  int ccol = lane & 15, crow = (lane >> 4) * 4;
#pragma unroll
  for (int i = 0; i < 4; ++i)
#pragma unroll
    for (int j = 0; j < 4; ++j) {
      int grow = m0 + wm * 64 + i * 16 + crow;
      int gcol = n0 + wn * 64 + j * 16 + ccol;
      if (!isv) {
#pragma unroll
        for (int r = 0; r < 4; ++r)
          qkb[(size_t)(grow + r) * 2048 + gcol] = f2bf(acc[i][j][r]);
      } else {
#pragma unroll
        for (int r = 0; r < 4; ++r)
          vb[(size_t)(grow + r) * II + gcol] = f2bf(acc[i][j][r]);
        int b8 = grow >> 9, sloc = grow & 511;
        int nh = gcol >> 7, d = gcol & 127;
        ushort4v o;
#pragma unroll
        for (int r = 0; r < 4; ++r) o[r] = f2bf(acc[i][j][r]);
        *(ushort4v*)&vbt[((size_t)(b8 * NHH + nh) * DHH + d) * SS + sloc] = o;
      }
    }
}

// ---------------- down GEMM: 8-wave core, split-K=4, atomic f32 accumulate into h ---------
__global__ __launch_bounds__(512) void k_gemm_down(const ushort* __restrict__ A,
                                                   const ushort* __restrict__ Bt,
                                                   float* __restrict__ Cf) {
  __shared__ ushort As[3][4096];
  __shared__ ushort Bs[3][4096];
  int tid = threadIdx.x;
  int wave = tid >> 6, lane = tid & 63;
  int wm = wave >> 1, wn = wave & 1;
  int bx, by; xcd_swz(&bx, &by);
  int m0 = by * 128, n0 = bx * 128;
  int k0 = blockIdx.z * 256;
  int srow = wave * 16 + (lane >> 2), scol = swz_scol(lane);
  const ushort* Ag = A + (size_t)(m0 + srow) * II + k0 + scol;
  const ushort* Bg = Bt + (size_t)(n0 + srow) * II + k0 + scol;
  int woff = wave * 512;
  int frow = lane & 15, fk = swz_fk(lane);
  int apo = (wm * 32 + frow) * 32 + fk;
  int bpo = (wn * 64 + frow) * 32 + fk;
  f32x4 acc[2][4] = {};
  gemm_core8(Ag, Bg, 256 / 32, &As[0][0], &Bs[0][0], woff, apo, bpo, acc);
  int ccol = lane & 15, crow = (lane >> 4) * 4;
#pragma unroll
  for (int i = 0; i < 2; ++i)
#pragma unroll
    for (int j = 0; j < 4; ++j) {
      int grow = m0 + wm * 32 + i * 16 + crow;
      int gcol = n0 + wn * 64 + j * 16 + ccol;
#pragma unroll
      for (int r = 0; r < 4; ++r)
        atomicAdd(&Cf[(size_t)(grow + r) * DD + gcol], acc[i][j][r]);
    }
}

// ---------------- causal conv (K=4) + SiLU, 8 channels/thread ----------------
__global__ __launch_bounds__(256) void k_conv_silu(const ushort* __restrict__ up,
                                                   const float* __restrict__ cw,
                                                   const float* __restrict__ cb,
                                                   ushort* __restrict__ out) {
  int g = blockIdx.x * 256 + threadIdx.x;
  int c8 = (g & 127) * 8;
  int row = g >> 7;
  int s = row & (SS - 1);
  float acc[8];
  float4 wv[8];
#pragma unroll
  for (int t = 0; t < 8; ++t) {
    acc[t] = cb[c8 + t];
    wv[t] = *(const float4*)(cw + (size_t)(c8 + t) * 4);
  }
#pragma unroll
  for (int j = 0; j < 4; ++j) {
    int so = s + j - 3;
    if (so >= 0) {
      ushort8 u = *(const ushort8*)&up[(size_t)(row + j - 3) * 2048 + c8];
#pragma unroll
      for (int t = 0; t < 8; ++t) {
        float wc = (j == 0) ? wv[t].x : (j == 1) ? wv[t].y : (j == 2) ? wv[t].z : wv[t].w;
        acc[t] += bf2f(u[t]) * wc;
      }
    }
  }
  ushort8 o;
#pragma unroll
  for (int t = 0; t < 8; ++t) {
    float sig = 1.0f / (1.0f + __expf(-acc[t]));
    o[t] = f2bf(acc[t] * sig);
  }
  *(ushort8*)&out[(size_t)row * II + c8] = o;
}

// ---------------- gate projections via MFMA: 4 waves, K-split + LDS reduce ----------------
__global__ __launch_bounds__(256) void k_gates_mfma(const ushort* __restrict__ qkb,
                                                    const ushort* __restrict__ vb,
                                                    const ushort* __restrict__ Wg,
                                                    const float* __restrict__ igb,
                                                    const float* __restrict__ fgb,
                                                    float* __restrict__ ig,
                                                    float* __restrict__ fg) {
  int tid = threadIdx.x;
  int wave = tid >> 6, lane = tid & 63;
  int row0 = blockIdx.x * 16;
  int l15 = lane & 15, lg = lane >> 4;
  int arow = row0 + l15;
  const ushort* qrow = qkb + (size_t)arow * 2048 + lg * 8;
  const ushort* vrow = vb + (size_t)arow * II + lg * 8;
  const ushort* wrow = Wg + (size_t)l15 * (3 * II) + lg * 8;
  f32x4 acc0 = {}, acc1 = {};
#pragma unroll
  for (int i = 0; i < 12; ++i) {
    int off = (wave * 12 + i) * 64;
    const ushort* ab = (off < 2048) ? (qrow + off) : (vrow + (off - 2048));
    short8 a0 = *(const short8*)(ab);
    short8 b0 = *(const short8*)(wrow + off);
    short8 a1 = *(const short8*)(ab + 32);
    short8 b1 = *(const short8*)(wrow + off + 32);
    acc0 = __builtin_amdgcn_mfma_f32_16x16x32_bf16(a0, b0, acc0, 0, 0, 0);
    acc1 = __builtin_amdgcn_mfma_f32_16x16x32_bf16(a1, b1, acc1, 0, 0, 0);
  }
  __shared__ f32x4 red[4][64];
  f32x4 part;
#pragma unroll
  for (int r = 0; r < 4; ++r) part[r] = acc0[r] + acc1[r];
  red[wave][lane] = part;
  __syncthreads();
  if (wave == 0) {
    f32x4 t0 = red[0][lane], t1 = red[1][lane], t2 = red[2][lane], t3 = red[3][lane];
    int o = l15;
#pragma unroll
    for (int r = 0; r < 4; ++r) {
      int row = row0 + lg * 4 + r;
      int bb = row >> 9, s = row & (SS - 1);
      float val = t0[r] + t1[r] + t2[r] + t3[r];
      if (o < NHH)
        ig[((size_t)bb * NHH + o) * SS + s] = val + igb[o];
      else
        fg[((size_t)bb * NHH + (o - NHH)) * SS + s] = val + fgb[o - NHH];
    }
  }
}

// ---------------- per-(b,n) scan: one wave per bn, shfl prefix ----------------
__global__ __launch_bounds__(64) void k_scan(const float* __restrict__ ig,
                                             const float* __restrict__ fg,
                                             float* __restrict__ e_g, float* __restrict__ M_g,
                                             float* __restrict__ maxd_g) {
  int bn = blockIdx.x;
  int lane = threadIdx.x;
  size_t base = (size_t)bn * SS + lane * 8;
  float4 f0 = *(const float4*)&fg[base];
  float4 f1 = *(const float4*)&fg[base + 4];
  float fv[8] = {f0.x, f0.y, f0.z, f0.w, f1.x, f1.y, f1.z, f1.w};
  float lf[8];
#pragma unroll
  for (int j = 0; j < 8; ++j) {
    float f = fv[j];
    lf[j] = (f >= 0.f) ? -log1pf(expf(-f)) : (f - log1pf(expf(f)));
  }
  float cum[8];
  float run = 0.f;
#pragma unroll
  for (int j = 0; j < 8; ++j) { run += lf[j]; cum[j] = run; }
  float inc = run;
#pragma unroll
  for (int off = 1; off < 64; off <<= 1) {
    float t = __shfl_up(inc, off);
    if (lane >= off) inc += t;
  }
  float exs = inc - run;
  float4 i0 = *(const float4*)&ig[base];
  float4 i1 = *(const float4*)&ig[base + 4];
  float igv[8] = {i0.x, i0.y, i0.z, i0.w, i1.x, i1.y, i1.z, i1.w};
  float cs[8], e[8];
#pragma unroll
  for (int j = 0; j < 8; ++j) {
    cs[j] = exs + cum[j];
    e[j] = igv[j] - cs[j];
  }
  float mcum[8];
  float mrun = -3.0e38f;
#pragma unroll
  for (int j = 0; j < 8; ++j) { mrun = fmaxf(mrun, e[j]); mcum[j] = mrun; }
  float minc = mrun;
#pragma unroll
  for (int off = 1; off < 64; off <<= 1) {
    float t = __shfl_up(minc, off);
    if (lane >= off) minc = fmaxf(minc, t);
  }
  float mex = __shfl_up(minc, 1);
  if (lane == 0) mex = -3.0e38f;
  float M[8], mdv[8];
#pragma unroll
  for (int j = 0; j < 8; ++j) {
    M[j] = fmaxf(mex, mcum[j]);
    mdv[j] = cs[j] + M[j];
  }
  *(float4*)&e_g[base] = make_float4(e[0], e[1], e[2], e[3]);
  *(float4*)&e_g[base + 4] = make_float4(e[4], e[5], e[6], e[7]);
  *(float4*)&M_g[base] = make_float4(M[0], M[1], M[2], M[3]);
  *(float4*)&M_g[base + 4] = make_float4(M[4], M[5], M[6], M[7]);
  *(float4*)&maxd_g[base] = make_float4(mdv[0], mdv[1], mdv[2], mdv[3]);
  *(float4*)&maxd_g[base + 4] = make_float4(mdv[4], mdv[5], mdv[6], mdv[7]);
}

// ---------------- mLSTM attention, MFMA bf16, async dbuf staging, fused GN epilogue --------
__global__ __launch_bounds__(256) void k_attn_mfma(const ushort* __restrict__ qkb,
                                                   const ushort* __restrict__ vbt,
                                                   const float* __restrict__ e_g,
                                                   const float* __restrict__ M_g,
                                                   const float* __restrict__ maxd_g,
                                                   const ushort* __restrict__ convact,
                                                   const ushort* __restrict__ up,
                                                   const float* __restrict__ gnw,
                                                   const float* __restrict__ skw,
                                                   ushort* __restrict__ hs) {
  __shared__ __align__(16) ushort K2[2][64 * 128];
  __shared__ __align__(16) ushort V2[2][128 * 64];
  __shared__ __align__(16) ushort w_s[4][16 * 72];
  __shared__ float e_s[SS];

  int tid = threadIdx.x;
  int wave = tid >> 6, lane = tid & 63;
  int xb = blockIdx.x;
  int stile = (xb & 1) ? (7 - (xb >> 1)) : (xb >> 1);
  int bn = blockIdx.y;
  int b = bn >> 3, n = bn & 7;
  int s0 = stile * 64;

  const size_t qbase = (size_t)(b * SS) * 2048 + (size_t)n * DHH;
  const size_t kbase = qbase + II;
  const size_t vtbase = (size_t)bn * DHH * SS;

  int l15 = lane & 15, lg = lane >> 4;
  int kg8 = lg * 8;
  int crow = lg * 4;
  int srow_base = s0 + wave * 16 + crow;

  e_s[tid] = e_g[(size_t)bn * SS + tid];
  e_s[tid + 256] = e_g[(size_t)bn * SS + tid + 256];

  short8 qf[4];
  {
    int qrow = s0 + wave * 16 + l15;
#pragma unroll
    for (int ks = 0; ks < 4; ++ks)
      qf[ks] = *(const short8*)&qkb[qbase + (size_t)qrow * 2048 + ks * 32 + kg8];
  }
  float Ms[4], md[4];
#pragma unroll
  for (int r = 0; r < 4; ++r) {
    Ms[r] = M_g[(size_t)bn * SS + srow_base + r];
    md[r] = maxd_g[(size_t)bn * SS + srow_base + r];
  }

  f32x4 acc[8] = {};
  float rsum[4] = {};
  const float rsq = 0.08838834764831845f;
  ushort* w_w = &w_s[wave][0];
  int ntt = stile + 1;

#pragma unroll
  for (int i = 0; i < 4; ++i) {
    int r = wave * 16 + i * 4 + (lane >> 4);
    int sp = (lane & 15) ^ (r & 7);
    async16(&qkb[kbase + (size_t)r * 2048 + sp * 8], &K2[0][(wave * 16 + i * 4) * 128]);
  }
#pragma unroll
  for (int i = 0; i < 4; ++i) {
    int d = wave * 32 + i * 8 + (lane >> 3);
    int sp = (lane & 7) ^ (d & 7);
    async16(&vbt[vtbase + (size_t)d * SS + sp * 8], &V2[0][(wave * 32 + i * 8) * 64]);
  }

  for (int tt = 0; tt < ntt; ++tt) {
    int cur = tt & 1;
    if (tt + 1 < ntt) {
      int t1 = (tt + 1) * 64;
      int nxt = cur ^ 1;
#pragma unroll
      for (int i = 0; i < 4; ++i) {
        int r = wave * 16 + i * 4 + (lane >> 4);
        int sp = (lane & 15) ^ (r & 7);
        async16(&qkb[kbase + (size_t)(t1 + r) * 2048 + sp * 8], &K2[nxt][(wave * 16 + i * 4) * 128]);
      }
#pragma unroll
      for (int i = 0; i < 4; ++i) {
        int d = wave * 32 + i * 8 + (lane >> 3);
        int sp = (lane & 7) ^ (d & 7);
        async16(&vbt[vtbase + (size_t)d * SS + t1 + sp * 8], &V2[nxt][(wave * 32 + i * 8) * 64]);
      }
      asm volatile("s_waitcnt vmcnt(8) lgkmcnt(0)" ::: "memory");
    } else {
      asm volatile("s_waitcnt vmcnt(0) lgkmcnt(0)" ::: "memory");
    }
    __builtin_amdgcn_s_barrier();

    int t0 = tt * 64;
    const ushort* Kc = &K2[cur][0];
    const ushort* Vc = &V2[cur][0];

    f32x4 s4[4];
#pragma unroll
    for (int ct = 0; ct < 4; ++ct) {
      f32x4 c = {};
      int ro = l15 + 16 * ct;
#pragma unroll
      for (int ks = 0; ks < 4; ++ks) {
        int sp = (ks * 4 + lg) ^ (ro & 7);
        short8 kf = *(const short8*)&Kc[ro * 128 + sp * 8];
        c = __builtin_amdgcn_mfma_f32_16x16x32_bf16(qf[ks], kf, c, 0, 0, 0);
      }
      s4[ct] = c;
    }
#pragma unroll
    for (int ct = 0; ct < 4; ++ct) {
      int t = t0 + l15 + 16 * ct;
      float e = e_s[t];
#pragma unroll
      for (int r = 0; r < 4; ++r) {
        int s = srow_base + r;
        float val = (t <= s) ? s4[ct][r] * rsq * __expf(e - Ms[r]) : 0.f;
        s4[ct][r] = val;
        w_w[(crow + r) * 72 + l15 + 16 * ct] = f2bf(val);
      }
    }
#pragma unroll
    for (int r = 0; r < 4; ++r) {
      float tmp = s4[0][r] + s4[1][r] + s4[2][r] + s4[3][r];
      tmp += __shfl_xor(tmp, 1);
      tmp += __shfl_xor(tmp, 2);
      tmp += __shfl_xor(tmp, 4);
      tmp += __shfl_xor(tmp, 8);
      rsum[r] += tmp;
    }
    short8 wf0 = *(const short8*)&w_w[l15 * 72 + kg8];
    short8 wf1 = *(const short8*)&w_w[l15 * 72 + 32 + kg8];
#pragma unroll
    for (int dt = 0; dt < 8; ++dt) {
      int d = dt * 16 + l15;
      int sp0 = lg ^ (d & 7);
      int sp1 = (lg + 4) ^ (d & 7);
      short8 vf0 = *(const short8*)&Vc[d * 64 + sp0 * 8];
      short8 vf1 = *(const short8*)&Vc[d * 64 + sp1 * 8];
      acc[dt] = __builtin_amdgcn_mfma_f32_16x16x32_bf16(wf0, vf0, acc[dt], 0, 0, 0);
      acc[dt] = __builtin_amdgcn_mfma_f32_16x16x32_bf16(wf1, vf1, acc[dt], 0, 0, 0);
    }
    __builtin_amdgcn_s_barrier();
  }

  float scl[4], sum[4] = {}, sq[4] = {};
#pragma unroll
  for (int r = 0; r < 4; ++r) {
    float nrm = fmaxf(fabsf(rsum[r]), __expf(-md[r]));
    scl[r] = 1.0f / (nrm + 1e-6f);
  }
#pragma unroll
  for (int dt = 0; dt < 8; ++dt)
#pragma unroll
    for (int r = 0; r < 4; ++r) {
      float v = acc[dt][r] * scl[r];
      sum[r] += v;
      sq[r] += v * v;
    }
#pragma unroll
  for (int r = 0; r < 4; ++r) {
#pragma unroll
    for (int off = 1; off <= 8; off <<= 1) {
      sum[r] += __shfl_xor(sum[r], off);
      sq[r] += __shfl_xor(sq[r], off);
    }
  }
  float mu[4], rstd[4];
#pragma unroll
  for (int r = 0; r < 4; ++r) {
    mu[r] = sum[r] * (1.0f / DHH);
    float var = sq[r] * (1.0f / DHH) - mu[r] * mu[r];
    rstd[r] = rsqrtf(var + 1e-5f);
  }
#pragma unroll
  for (int dt = 0; dt < 8; ++dt) {
    int c = dt * 16 + l15;
    float gw = gnw[n * DHH + c];
    float sw = skw[n * DHH + c];
#pragma unroll
    for (int r = 0; r < 4; ++r) {
      size_t ridx = (size_t)(b * SS + srow_base + r);
      float v = acc[dt][r] * scl[r];
      float hn = (v - mu[r]) * rstd[r] * gw;
      float ca = bf2f(convact[ridx * II + n * DHH + c]);
      float z = bf2f(up[ridx * 2048 + II + n * DHH + c]);
      float sz = z / (1.0f + __expf(-z));
      hs[ridx * II + n * DHH + c] = f2bf((hn + sw * ca) * sz);
    }
  }
}

// ---------------- final LN(last row) + 2-layer head ----------------
__global__ __launch_bounds__(256) void k_head(const float* __restrict__ h,
                                              const float* __restrict__ pw,
                                              const float* __restrict__ pb,
                                              const float* __restrict__ w1,
                                              const float* __restrict__ b1,
                                              const float* __restrict__ w2,
                                              const float* __restrict__ b2,
                                              float* __restrict__ out) {
  int b = blockIdx.x;
  int tid = threadIdx.x;
  __shared__ float last[DD];
  __shared__ float hid[H1H];
  __shared__ float ss[4], sqs[4];
  const float* row = h + ((size_t)b * SS + SS - 1) * DD;
  float v0 = row[tid], v1 = row[tid + 256];
  float s = v0 + v1, sq = v0 * v0 + v1 * v1;
  for (int off = 32; off; off >>= 1) {
    s += __shfl_down(s, off);
    sq += __shfl_down(sq, off);
  }
  int wid = tid >> 6, lane = tid & 63;
  if (lane == 0) { ss[wid] = s; sqs[wid] = sq; }
  __syncthreads();
  if (tid == 0) {
    ss[0] = ss[0] + ss[1] + ss[2] + ss[3];
    sqs[0] = sqs[0] + sqs[1] + sqs[2] + sqs[3];
  }
  __syncthreads();
  float mean = ss[0] * (1.0f / DD);
  float var = sqs[0] * (1.0f / DD) - mean * mean;
  float r = rsqrtf(var + 1e-5f);
  last[tid] = (v0 - mean) * r * pw[tid] + pb[tid];
  last[tid + 256] = (v1 - mean) * r * pw[tid + 256] + pb[tid + 256];
  __syncthreads();
  if (tid < H1H) {
    float a = b1[tid];
    for (int d2 = 0; d2 < DD; ++d2) a += last[d2] * w1[(size_t)d2 * H1H + tid];
    hid[tid] = fmaxf(a, 0.f);
  }
  __syncthreads();
  if (tid < OUTO) {
    float a = b2[tid];
#pragma unroll
    for (int j2 = 0; j2 < H1H; ++j2) a += hid[j2] * w2[(size_t)j2 * OUTO + tid];
    out[(size_t)b * OUTO + tid] = a;
  }
}

extern "C" void kernel_launch(void* const* d_in, const int* in_sizes, int n_in,
                              void* d_out, int out_size, void* d_ws, size_t ws_size,
                              hipStream_t stream) {
  (void)in_sizes; (void)n_in; (void)out_size; (void)ws_size;
  const float* x    = (const float*)d_in[0];
  const float* in_w = (const float*)d_in[1];
  const float* in_b = (const float*)d_in[2];
  const float* ln_w = (const float*)d_in[3];
  const float* ln_b = (const float*)d_in[4];
  const float* up_w = (const float*)d_in[5];
  const float* conv_w = (const float*)d_in[6];
  const float* conv_b = (const float*)d_in[7];
  const float* q_w  = (const float*)d_in[8];
  const float* k_w  = (const float*)d_in[9];
  const float* v_w  = (const float*)d_in[10];
  const float* ig_w = (const float*)d_in[11];
  const float* ig_b = (const float*)d_in[12];
  const float* fg_w = (const float*)d_in[13];
  const float* fg_b = (const float*)d_in[14];
  const float* gn_w = (const float*)d_in[15];
  const float* sk_w = (const float*)d_in[16];
  const float* dn_w = (const float*)d_in[17];
  const float* po_w = (const float*)d_in[18];
  const float* po_b = (const float*)d_in[19];
  const float* h1_w = (const float*)d_in[20];
  const float* h1_b = (const float*)d_in[21];
  const float* h2_w = (const float*)d_in[22];
  const float* h2_b = (const float*)d_in[23];

  float* h = (float*)d_ws;                              // 2M f32
  ushort* xn_bf = (ushort*)(h + 2097152);               // 2M bf16
  ushort* up_bf = xn_bf + 2097152;                      // 8M
  ushort* conv_bf = up_bf + 8388608;                    // 4M
  ushort* qkb = conv_bf + 4194304;                      // 8M (q | k fused)
  ushort* vb = qkb + 8388608;                           // 4M
  ushort* vbt = vb + 4194304;                           // 4M (per-head V^T)
  ushort* hs_bf = vbt + 4194304;                        // 4M
  ushort* wt_up = hs_bf + 4194304;                      // 2 x 1M
  ushort* wt_qk = wt_up + 2097152;                      // 2 x 2M
  ushort* wt_v  = wt_qk + 4194304;                      // 2 x 1M
  ushort* wt_dn = wt_v + 2097152;                       // 2 x 0.5M
  ushort* Wg = wt_dn + 1048576;                         // 2 x 49152
  float* igb_ = (float*)(Wg + 98304);
  float* fgb_ = igb_ + 32768;
  float* e_g  = fgb_ + 32768;
  float* M_g  = e_g + 32768;
  float* md_g = M_g + 32768;

  k_pre<<<2584, 256, 0, stream>>>(x, in_w, in_b, ln_w, ln_b, h, xn_bf,
                                  up_w, q_w, k_w, v_w, dn_w, ig_w, fg_w,
                                  wt_up, wt_qk, wt_v, wt_dn, Wg);
  for (int l = 0; l < 2; ++l) {
    if (l) k_layernorm<<<BS, 256, 0, stream>>>(h, ln_w + l * DD, ln_b + l * DD, xn_bf);
    k_gemm_up<<<dim3(16, 32), 512, 0, stream>>>(xn_bf, wt_up + (size_t)l * 1048576, up_bf);
    k_conv_silu<<<BS * II / 8 / 256, 256, 0, stream>>>(up_bf, conv_w + l * II * KK,
                                                       conv_b + l * II, conv_bf);
    k_gemm_qkv<<<dim3(24, 32), 256, 0, stream>>>(conv_bf, up_bf,
                                                 wt_qk + (size_t)l * 2097152,
                                                 wt_v + (size_t)l * 1048576,
                                                 qkb, vb, vbt);
    k_gates_mfma<<<256, 256, 0, stream>>>(qkb, vb, Wg + (size_t)l * 49152,
                                          ig_b + l * NHH, fg_b + l * NHH, igb_, fgb_);
    k_scan<<<BB * NHH, 64, 0, stream>>>(igb_, fgb_, e_g, M_g, md_g);
    k_attn_mfma<<<dim3(8, BB * NHH), 256, 0, stream>>>(qkb, vbt, e_g, M_g, md_g,
                                                       conv_bf, up_bf,
                                                       gn_w + l * II, sk_w + l * II, hs_bf);
    k_gemm_down<<<dim3(4, 32, 4), 512, 0, stream>>>(hs_bf, wt_dn + (size_t)l * 524288, h);
  }
  k_head<<<BB, 256, 0, stream>>>(h, po_w, po_b, h1_w, h1_b, h2_w, h2_b, (float*)d_out);
}